// Round 13
// baseline (241.144 us; speedup 1.0000x reference)
//
#include <hip/hip_runtime.h>

typedef unsigned short u16;
typedef unsigned u32;
typedef __bf16 bf16x8 __attribute__((ext_vector_type(8)));
typedef float f32x4 __attribute__((ext_vector_type(4)));
typedef float f32x16 __attribute__((ext_vector_type(16)));

#define MFMA16(A,B,C) __builtin_amdgcn_mfma_f32_16x16x32_bf16((A),(B),(C),0,0,0)
#define MFMA32(A,B,C) __builtin_amdgcn_mfma_f32_32x32x16_bf16((A),(B),(C),0,0,0)

__device__ __forceinline__ u16 f2b(float f){
  union { float f; unsigned u; } X; X.f = f;
  unsigned r = X.u + 0x7FFFu + ((X.u >> 16) & 1u);
  return (u16)(r >> 16);
}
__device__ __forceinline__ float b2f(u16 h){
  union { unsigned u; float f; } X; X.u = ((unsigned)h) << 16; return X.f;
}
__device__ __forceinline__ bf16x8 ld_frag(const u16* p){
  union { uint4 u; bf16x8 v; } U; U.u = *(const uint4*)p; return U.v;
}
// pack two f32 -> one u32 of 2 bf16 (RNE). No builtin on gfx950 -> inline asm.
__device__ __forceinline__ u32 pkbf(float a, float b){
  u32 r; asm("v_cvt_pk_bf16_f32 %0, %1, %2" : "=v"(r) : "v"(a), "v"(b)); return r;
}
// swap lower-32-lane half of x with upper-32-lane half of y (both outputs usable)
__device__ __forceinline__ void pl32swap(u32& x, u32& y){
  auto r = __builtin_amdgcn_permlane32_swap(x, y, false, false);
  x = r[0]; y = r[1];
}
// async global->LDS, 16B per lane, wave-uniform LDS base + lane*16
__device__ __forceinline__ void gld16(const u16* g, u16* l){
  __builtin_amdgcn_global_load_lds(
      (const __attribute__((address_space(1))) u32*)g,
      (__attribute__((address_space(3))) u32*)l, 16, 0, 0);
}

// ---------------- prep bodies ----------------
// wB[tap121][chunk16][oc32][ci16]: oc<16 -> conv7 (zero-padded), oc>=16 -> conv11.
// wC[tap9][chunk16][oc32][ci16]:  oc<16 -> conv1, oc>=16 -> zero.
// w2t[co256][k160] TAP-MAJOR. (wB/wC alias y_t — kv runs concurrently with qconv.)
// tail ranges: pooled[1024] zero + xp HALO zero (replaces the 12MB memset; halo is
// disjoint from prep_x's interior writes, so no intra-kernel ordering needed).
__device__ __forceinline__ void prep_w_body(int i,
    const float* __restrict__ dw1, const float* __restrict__ dw2,
    const float* __restrict__ cw1, const float* __restrict__ kw,
    const float* __restrict__ vw,  const float* __restrict__ cw2,
    u16* __restrict__ wB, u16* __restrict__ wC,
    u16* __restrict__ kwt, u16* __restrict__ vwt, u16* __restrict__ w2t,
    float* __restrict__ pooled, u16* __restrict__ xp){
  const int NB = 991232, NC = 73728, NK = 8192, NV = 65536, N2 = 40960;
  if(i < NB){
    int tap = i >> 13, rem = i & 8191;
    int chunk = rem >> 9, r2 = rem & 511;
    int oc = r2 >> 4, ci = chunk*16 + (r2 & 15);
    int dy = tap / 11, dx = tap - dy*11;
    float v;
    if(oc < 16){
      v = (dy >= 2 && dy <= 8 && dx >= 2 && dx <= 8) ? dw1[(oc*256 + ci)*49 + (dy-2)*7 + (dx-2)] : 0.f;
    } else {
      v = dw2[((oc-16)*256 + ci)*121 + tap];
    }
    wB[i] = f2b(v);
    return;
  }
  i -= NB;
  if(i < NC){
    int tap = i >> 13, rem = i & 8191;
    int chunk = rem >> 9, r2 = rem & 511;
    int oc = r2 >> 4, ci = chunk*16 + (r2 & 15);
    wC[i] = (oc < 16) ? f2b(cw1[(oc*256 + ci)*9 + tap]) : (u16)0;
    return;
  }
  i -= NC;
  if(i < NK){ kwt[i] = f2b(kw[i]); return; }
  i -= NK;
  if(i < NV){ vwt[i] = f2b(vw[i]); return; }
  i -= NV;
  if(i < N2){
    int co = i/160, kk = i - co*160;
    int tap = kk >> 4, ci = kk & 15;
    w2t[i] = (tap < 9) ? f2b(cw2[co*144 + ci*9 + tap]) : (u16)0;
    return;
  }
  i -= N2;
  if(i < 1024){ pooled[i] = 0.f; return; }
  i -= 1024;
  if(i < 116736){   // xp halo: 4 b x 16 chunks x 1824 halo px, 32B each
    int b = i / 29184;
    int r1 = i - b*29184;
    int chunk = r1 / 1824;
    int p = r1 - chunk*1824;
    int y, x;
    if(p < 800){ int r = p / 80; x = p - r*80; y = (r < 5) ? r : r + 64; }
    else { int j = p - 800; int cc = j & 15; y = 5 + (j >> 4); x = (cc < 5) ? cc : cc + 64; }
    uint4* dst = (uint4*)&xp[(((size_t)(b*16 + chunk)*74 + y)*80 + x)*16];
    dst[0] = make_uint4(0u,0u,0u,0u);
    dst[1] = make_uint4(0u,0u,0u,0u);
    return;
  }
}

// x NCHW fp32 -> padded CHUNK-MAJOR xp[b][chunk16][y+5][x+5][ci16] bf16 (interior only)
__device__ __forceinline__ void prep_x_body(int bid, int t, float* tile /*[32][33] shared*/,
    const float* __restrict__ x, u16* __restrict__ xp){
  const int b = bid >> 10, rem = bid & 1023;
  const int c0 = (rem >> 7) << 5, m0 = (rem & 127) << 5;
  { const int cg = t >> 5, mm = t & 31;
    #pragma unroll
    for(int i=0;i<4;i++)
      tile[(cg*4+i)*33 + mm] = x[((size_t)(b*256 + c0 + cg*4 + i) << 12) + m0 + mm];
  }
  __syncthreads();
  { const int cp = (t & 15) << 1, mloc = t >> 4;
    #pragma unroll
    for(int half = 0; half < 2; ++half){
      const int ml = half*16 + mloc;
      const int m = m0 + ml;
      const int yy = (m >> 6) + 5, xx = (m & 63) + 5;
      const int ci = c0 + cp;
      const int chunk = ci >> 4, wi = ci & 15;
      u16 lo = f2b(tile[cp*33 + ml]), hi = f2b(tile[(cp+1)*33 + ml]);
      *(unsigned*)&xp[(((size_t)(b*16 + chunk)*74 + yy)*80 + xx)*16 + wi] = ((unsigned)hi << 16) | lo;
    }
  }
}

// ---------------- K_prep: fused prep_x + prep_w + pooled/halo zero ----------------
__global__ __launch_bounds__(256) void k_prep(
    const float* __restrict__ x, u16* __restrict__ xp,
    const float* __restrict__ dw1, const float* __restrict__ dw2,
    const float* __restrict__ cw1, const float* __restrict__ kw,
    const float* __restrict__ vw,  const float* __restrict__ cw2,
    u16* __restrict__ wB, u16* __restrict__ wC,
    u16* __restrict__ kwt, u16* __restrict__ vwt, u16* __restrict__ w2t,
    float* __restrict__ pooled){
  __shared__ float tile[32*33];
  const int bid = blockIdx.x;
  if(bid < 4096){
    prep_x_body(bid, threadIdx.x, tile, x, xp);
  } else {
    prep_w_body((bid - 4096)*256 + threadIdx.x, dw1, dw2, cw1, kw, vw, cw2, wB, wC, kwt, vwt, w2t, pooled, xp);
  }
}

// ---------------- qconv body: fused conv7+conv11+conv1, 32x32x16 MFMA ----------------
// The 242.5µs-verified structure (measured optimum of the tile-geometry space: r8's
// kq-split and r9's 2-row/wave both regressed via register squeeze). 4 output rows/block
// (512 qconv blocks = 2/CU); wave wv owns row y0+wv, BOTH x-halves (2 MFMAs per B-frag);
// fully unrolled dy with 2-deep register pipeline of the 11 B-frags.
__device__ __forceinline__ void qconv_body(int bid, int t, u16* buf /*35840B shared*/,
    const u16* __restrict__ xp, const u16* __restrict__ wB, const u16* __restrict__ wC,
    u16* __restrict__ qp){
  const int rg = bid & 15, b = (bid >> 4) & 3, kq = bid >> 6;
  const int y0 = rg << 2;
  const int wv = t >> 6, lane = t & 63;
  const int m = lane & 31, kh = lane >> 5;
  const int laneoff = m*16 + kh*8;
  const f32x16 z16 = {0.f,0.f,0.f,0.f,0.f,0.f,0.f,0.f,0.f,0.f,0.f,0.f,0.f,0.f,0.f,0.f};
  f32x16 accA = z16, accB = z16, acc1A = z16, acc1B = z16;

  #pragma unroll 1
  for(int c = 0; c < 2; ++c){
    const int chunk = kq*2 + c;
    const uint4* src = (const uint4*)(xp + ((size_t)((b*16 + chunk)*74 + y0))*1280);
    __syncthreads();
    for(int e = t; e < 2240; e += 256){
      ((uint4*)buf)[(e & 1)*1120 + (e >> 1)] = src[e];
    }
    __syncthreads();
    const u16* wBc = wB + chunk*512 + laneoff;
    const u16* wCc = wC + chunk*512 + laneoff;
    const u16* ap = buf + kh*8960 + (wv*80 + m)*8;
    bf16x8 Brow[2][11];
    #pragma unroll
    for(int dx = 0; dx < 11; ++dx) Brow[0][dx] = ld_frag(wBc + dx*8192);
    #pragma unroll
    for(int dy = 0; dy < 11; ++dy){
      if(dy < 10){
        const u16* wnext = wBc + (dy+1)*11*8192;
        #pragma unroll
        for(int dx = 0; dx < 11; ++dx) Brow[(dy+1)&1][dx] = ld_frag(wnext + dx*8192);
      }
      const u16* rowp = ap + dy*640;
      #pragma unroll
      for(int dx = 0; dx < 11; ++dx){
        bf16x8 B = Brow[dy&1][dx];
        bf16x8 A0 = ld_frag(rowp + dx*8);
        bf16x8 A1 = ld_frag(rowp + dx*8 + 256);
        accA = MFMA32(A0, B, accA);
        accB = MFMA32(A1, B, accB);
        if(dy >= 4 && dy <= 6 && dx >= 4 && dx <= 6){
          bf16x8 B1 = ld_frag(wCc + ((dy-4)*3 + (dx-4))*8192);
          acc1A = MFMA32(A0, B1, acc1A);
          acc1B = MFMA32(A1, B1, acc1B);
        }
      }
    }
  }

  u16* qb = qp + ((size_t)kq*16384 + (b << 12) + (y0 + wv)*64) * 48;
  #pragma unroll
  for(int reg = 0; reg < 16; ++reg){
    const int row = (reg & 3) + ((reg >> 2) << 3) + (kh << 2);
    qb[row*48 + m] = f2b(accA[reg]);
    qb[(32 + row)*48 + m] = f2b(accB[reg]);
    if(m < 16){
      qb[row*48 + 32 + m] = f2b(acc1A[reg]);
      qb[(32 + row)*48 + 32 + m] = f2b(acc1B[reg]);
    }
  }
}

// ---------------- kv body: 1x1 convs, 4-way ct-split ----------------
// vt written in MFMA-B-fragment order (k_attn stages it with a linear global_load_lds copy;
// zero LDS bank conflicts by construction).
__device__ __forceinline__ void kv_body(int bid, int tid,
    const u16* __restrict__ xp, const u16* __restrict__ vwt, const u16* __restrict__ kwt,
    const float* __restrict__ vb, const float* __restrict__ kb,
    u16* __restrict__ vt, u16* __restrict__ k_t){
  const int h = bid & 3, blk = (bid >> 2) & 63, b = bid >> 8;
  const int wv = tid >> 6, lane = tid & 63;
  const int col = lane & 15, quad = lane >> 4;
  const int m0 = (blk << 6) + (wv << 4);
  f32x4 z = {0.f,0.f,0.f,0.f};
  f32x4 av[4], ak[2];
  #pragma unroll
  for(int i=0;i<4;i++) av[i] = z;
  ak[0] = z; ak[1] = z;
  const int m = m0 + col;
  const int py = (m >> 6) + 5, pxx = (m & 63) + 5;
  #pragma unroll 1
  for(int ch = 0; ch < 8; ++ch){
    const int cio = ch*32 + quad*8;
    const int chunk = cio >> 4, wi = cio & 15;
    bf16x8 xf = ld_frag(xp + (((size_t)(b*16 + chunk)*74 + py)*80 + pxx)*16 + wi);
    #pragma unroll
    for(int ct2 = 0; ct2 < 4; ++ct2){
      bf16x8 wf = ld_frag(vwt + (((h*4 + ct2)*16 + col) << 8) + cio);
      av[ct2] = MFMA16(wf, xf, av[ct2]);
    }
    if(h == 0){
      #pragma unroll
      for(int kt = 0; kt < 2; ++kt){
        bf16x8 kf = ld_frag(kwt + ((kt*16 + col) << 8) + cio);
        ak[kt] = MFMA16(xf, kf, ak[kt]);
      }
    }
  }
  const size_t kgb = ((size_t)(b*256 + (m0 >> 4)));
  const int hi2 = col >> 3, j = col & 7;
  #pragma unroll
  for(int ct2 = 0; ct2 < 4; ++ct2){
    #pragma unroll
    for(int r = 0; r < 4; ++r){
      const int c = (h*4 + ct2)*16 + quad*4 + r;
      vt[((((kgb*8 + (c >> 5))*2 + hi2)*32) + (c & 31))*8 + j] = f2b(av[ct2][r] + vb[c]);
    }
  }
  if(h == 0){
    #pragma unroll
    for(int kt = 0; kt < 2; ++kt){
      #pragma unroll
      for(int r = 0; r < 4; ++r){
        const int mq = b*4096 + m0 + quad*4 + r;
        k_t[mq*32 + kt*16 + col] = f2b((ak[kt][r] + kb[kt*16 + col]) );
      }
    }
  }
}

// ---------------- K_qkv: fused qconv (bid<512) + kv (bid>=512) ----------------
// kv is independent of qconv (both read xp, write disjoint outputs) and qconv runs at
// only 2 blocks/CU — kv blocks fill the idle capacity instead of a serial launch.
__global__ __launch_bounds__(256, 2) void k_qconv_kv(
    const u16* __restrict__ xp, const u16* __restrict__ wB, const u16* __restrict__ wC,
    u16* __restrict__ qp,
    const u16* __restrict__ vwt, const u16* __restrict__ kwt,
    const float* __restrict__ vb, const float* __restrict__ kb,
    u16* __restrict__ vt, u16* __restrict__ k_t){
  __shared__ __align__(16) u16 buf[17920];   // used by qconv path only
  const int bid = blockIdx.x;
  if(bid < 512) qconv_body(bid, threadIdx.x, buf, xp, wB, wC, qp);
  else          kv_body(bid - 512, threadIdx.x, xp, vwt, kwt, vb, kb, vt, k_t);
}

// ---------------- K2b: combine 8 bf16 partials, bias, silu. Q scaled by log2(e) ----------------
__global__ __launch_bounds__(256) void k_qfin(
    const u16* __restrict__ qp, const float* __restrict__ b7,
    const float* __restrict__ b11, const float* __restrict__ b1,
    u16* __restrict__ q_t, u16* __restrict__ t1){
  const int t = threadIdx.x, wv = t >> 6, lane = t & 63;
  const int px = blockIdx.x*4 + wv;
  if(lane >= 48) return;
  const size_t off = (size_t)px*48 + lane;
  float s = 0.f;
  #pragma unroll
  for(int sp = 0; sp < 8; ++sp) s += b2f(qp[off + (size_t)sp*786432]);
  const float LOG2E = 1.44269504f;
  if(lane < 16){
    q_t[px*32 + lane] = f2b((s + b7[lane]) * LOG2E);
  } else if(lane < 32){
    q_t[px*32 + lane] = f2b((s + b11[lane - 16]) * LOG2E);
  } else {
    float v = s + b1[lane - 32];
    t1[px*16 + lane - 32] = f2b(v / (1.f + __expf(-v)));
  }
}

// ---------------- attn body: dedup softmax, counted-vmcnt pipeline (r5-verified) ----------------
// ks=2 (2048 keys / 32 iters per block). r13: ONLY change vs the 235.7µs-verified r11
// body is T5 s_setprio(1) around the MFMA clusters (setprio is data-inert — scheduler
// priority only). exp2f RESTORED (r12's raw v_exp_f32 asm hid the TRANS-op result-read
// hazard from the compiler -> stale-register reads -> absmax 0.152 failure).
__device__ __forceinline__ void attn_body(int bid, int t, u16* Vs /*2x16384 u16 shared*/,
    const u16* __restrict__ q_t, const u16* __restrict__ k_t,
    const u16* __restrict__ vt, u16* __restrict__ Op,
    float* __restrict__ lsav){
  const int q0 = (bid & 31) << 7, b = (bid >> 5) & 3, ks = bid >> 7;  // ks 0..1
  const int wv = t >> 6, lane = t & 63;
  const int cq = lane & 31, hi = lane >> 5;

  const u16* qrow = q_t + ((size_t)(b*4096 + q0 + wv*32 + cq) << 5) + hi*8;
  const bf16x8 qf0 = ld_frag(qrow), qf1 = ld_frag(qrow + 16);
  const u16* kbase = k_t + ((size_t)(b*4096 + ks*2048 + cq) << 5) + hi*8;
  const u16* vsrc = vt + ((size_t)(b*256 + ks*128) << 12);

  const f32x16 z16 = {0.f,0.f,0.f,0.f,0.f,0.f,0.f,0.f,0.f,0.f,0.f,0.f,0.f,0.f,0.f,0.f};
  f32x16 acc[8];
  #pragma unroll
  for(int i=0;i<8;i++) acc[i] = z16;
  float lp0=0.f, lp1=0.f, lp2=0.f, lp3=0.f;

  // prologue: stage iter 0 (32KB linear), then K frags for iter 0 (order pinned)
  #pragma unroll
  for(int s = 0; s < 8; ++s)
    gld16(vsrc + (size_t)(s*256 + t)*8, Vs + (s*256 + (wv << 6))*8);
  __builtin_amdgcn_sched_barrier(0);
  bf16x8 kc0 = ld_frag(kbase),        kc1 = ld_frag(kbase + 16);
  bf16x8 kc2 = ld_frag(kbase + 1024), kc3 = ld_frag(kbase + 1040);

  #pragma unroll 1
  for(int it = 0; it < 32; ++it){
    const int cur = it & 1;
    asm volatile("s_waitcnt vmcnt(4)" ::: "memory");   // stage(it) landed; K(it) may remain
    __builtin_amdgcn_s_barrier();
    __builtin_amdgcn_sched_barrier(0);
    const bf16x8 ka0 = kc0, ka1 = kc1, ka2 = kc2, ka3 = kc3;
    if(it < 31){
      const u16* gb = vsrc + ((size_t)(it + 1) << 14);
      #pragma unroll
      for(int s = 0; s < 8; ++s)
        gld16(gb + (size_t)(s*256 + t)*8, Vs + (cur ^ 1)*16384 + (s*256 + (wv << 6))*8);
      __builtin_amdgcn_sched_barrier(0);   // pin gld16 before kc loads (in-order vmcnt retire)
      const u16* kpn = kbase + ((size_t)(it + 1) << 11);
      kc0 = ld_frag(kpn);        kc1 = ld_frag(kpn + 16);
      kc2 = ld_frag(kpn + 1024); kc3 = ld_frag(kpn + 1040);
    }
    const u16* Vb = Vs + cur*16384 + hi*256 + cq*8;   // lane-linear frag base
    #pragma unroll
    for(int sub = 0; sub < 2; ++sub){
      const bf16x8 kf0 = sub ? ka2 : ka0;
      const bf16x8 kf1 = sub ? ka3 : ka1;
      __builtin_amdgcn_s_setprio(1);
      f32x16 S = MFMA32(kf0, qf0, z16);
      S = MFMA32(kf1, qf1, S);
      __builtin_amdgcn_s_setprio(0);
      float p[16];
      #pragma unroll
      for(int rr = 0; rr < 16; ++rr) p[rr] = exp2f(S[rr]);
      #pragma unroll
      for(int rr = 0; rr < 16; rr += 4){
        lp0 += p[rr]; lp1 += p[rr+1]; lp2 += p[rr+2]; lp3 += p[rr+3];
      }
      u32 a0 = pkbf(p[0], p[1]),   b0 = pkbf(p[4], p[5]);
      u32 a1 = pkbf(p[2], p[3]),   b1 = pkbf(p[6], p[7]);
      u32 c0 = pkbf(p[8], p[9]),   d0 = pkbf(p[12], p[13]);
      u32 c1 = pkbf(p[10], p[11]), d1 = pkbf(p[14], p[15]);
      pl32swap(a0, b0); pl32swap(a1, b1); pl32swap(c0, d0); pl32swap(c1, d1);
      union { u32 w[4]; bf16x8 v; } A0, A1;
      A0.w[0] = a0; A0.w[1] = a1; A0.w[2] = b0; A0.w[3] = b1;
      A1.w[0] = c0; A1.w[1] = c1; A1.w[2] = d0; A1.w[3] = d1;
      const u16* f0 = Vb + sub*8192;
      __builtin_amdgcn_s_setprio(1);
      #pragma unroll
      for(int ct = 0; ct < 8; ++ct){
        acc[ct] = MFMA32(A0.v, ld_frag(f0 + ct*512),        acc[ct]);
        acc[ct] = MFMA32(A1.v, ld_frag(f0 + 4096 + ct*512), acc[ct]);
      }
      __builtin_amdgcn_s_setprio(0);
    }
  }

  float lt = lp0 + lp1 + lp2 + lp3;
  lt += __shfl_xor(lt, 32);
  if(lane < 32)
    lsav[ks*16384 + b*4096 + q0 + wv*32 + cq] = lt;
  const float invl = 1.f / lt;
  u16* ob = Op + (((size_t)(ks*16384 + b*4096 + q0 + wv*32)) << 8) + cq;
  #pragma unroll
  for(int reg = 0; reg < 16; ++reg){
    const int row = (reg & 3) + ((reg >> 2) << 3) + (hi << 2);
    const float inv = __shfl(invl, row);
    u16* orow = ob + ((size_t)row << 8);
    #pragma unroll
    for(int ct = 0; ct < 8; ++ct)
      orow[ct*32] = f2b(acc[ct][reg] * inv);
  }
}

// ---------------- conv2 body: 3x3 16->256, tap-major im2col, 4-way oc-split ----------------
__device__ __forceinline__ void conv2_body(int bid, int t, u16* im_s /*[64][168]*/, float* pool_s /*[64]*/,
    const u16* __restrict__ t1, const u16* __restrict__ w2t, const float* __restrict__ b2,
    u16* __restrict__ y_t, float* __restrict__ pooled){
  const int h = bid & 3, y = (bid >> 2) & 63, b = bid >> 8;
  if(t < 64) pool_s[t] = 0.f;
  const u16* t1b = t1 + ((size_t)(b*4096) << 4);
  { const int px = t >> 2, ci0 = (t & 3) << 2;
    #pragma unroll
    for(int tap = 0; tap < 9; ++tap){
      const int ky = (tap*11) >> 5, kx = tap - ky*3;
      const int ryy = y + ky - 1, rxx = px + kx - 1;
      uint2 val = make_uint2(0u, 0u);
      if((unsigned)ryy < 64u && (unsigned)rxx < 64u)
        val = *(const uint2*)(t1b + (((ryy << 6) + rxx) << 4) + ci0);
      *(uint2*)(im_s + px*168 + tap*16 + ci0) = val;
    }
    for(int e = t; e < 1024; e += 256){ im_s[(e >> 4)*168 + 144 + (e & 15)] = 0; }
  }
  __syncthreads();
  const int wv = t >> 6, lane = t & 63, col = lane & 15, quad = lane >> 4;
  const f32x4 z = {0.f,0.f,0.f,0.f};
  f32x4 acc[4];
  #pragma unroll
  for(int i=0;i<4;i++) acc[i] = z;
  #pragma unroll
  for(int ch = 0; ch < 5; ++ch){
    bf16x8 af = ld_frag(im_s + (wv*16 + col)*168 + ch*32 + quad*8);
    #pragma unroll
    for(int j = 0; j < 4; ++j){
      bf16x8 wf = ld_frag(w2t + ((h*4 + j)*16 + col)*160 + ch*32 + quad*8);
      acc[j] = MFMA16(af, wf, acc[j]);
    }
  }
  const int m0 = (y << 6) + (wv << 4) + (quad << 2);
  #pragma unroll
  for(int j = 0; j < 4; ++j){
    const int c = (h*4 + j)*16 + col;
    const float bias = b2[c];
    float s = 0.f;
    #pragma unroll
    for(int r = 0; r < 4; ++r){
      float v = acc[j][r] + bias;
      y_t[((size_t)(b*4096 + m0 + r) << 8) + c] = f2b(v);
      s += v;
    }
    s += __shfl_xor(s, 16); s += __shfl_xor(s, 32);
    if(quad == 0) atomicAdd(&pool_s[c - h*64], s);
  }
  __syncthreads();
  if(t < 64) atomicAdd(&pooled[b*256 + h*64 + t], pool_s[t]);
}

// ---------------- K_ac: fused attn (bid<256) + conv2 (bid>=256) ----------------
// attn grid 256 (ks=2); conv2's 1024 blocks fill the freed residency. Shared mem union:
// attn uses all 64KB; conv2 carves im (21504B) + pool (256B) from the same block.
// conv2 deliberately does NOT get setprio — attn is the long pole.
__global__ __launch_bounds__(256, 2) void k_attn_conv2(
    const u16* __restrict__ q_t, const u16* __restrict__ k_t,
    const u16* __restrict__ vt, u16* __restrict__ Op, float* __restrict__ lsav,
    const u16* __restrict__ t1, const u16* __restrict__ w2t, const float* __restrict__ b2,
    u16* __restrict__ y_t, float* __restrict__ pooled){
  __shared__ __align__(16) u16 shm[32768];   // 65536 B
  const int bid = blockIdx.x;
  if(bid < 256) attn_body(bid, threadIdx.x, shm, q_t, k_t, vt, Op, lsav);
  else          conv2_body(bid - 256, threadIdx.x, shm, (float*)(shm + 10752), t1, w2t, b2, y_t, pooled);
}

// ---------------- K7: final combine + fused 2-way K-split merge + fused SE gate ----------------
__global__ __launch_bounds__(256) void k_final(
    const u16* __restrict__ Op, const u16* __restrict__ y_t, const float* __restrict__ x,
    const float* __restrict__ lsav, const float* __restrict__ pooled,
    const float* __restrict__ sew, const float* __restrict__ seb,
    const float* __restrict__ g1p, const float* __restrict__ g2p,
    float* __restrict__ out){
  __shared__ float tO[32][65];
  __shared__ float tY[32][65];
  __shared__ float gate_l[32];
  const int bid = blockIdx.x;
  const int b = bid >> 9, rem = bid & 511;
  const int c0 = (rem >> 6) << 5, m0 = (rem & 63) << 6;
  const int t = threadIdx.x;
  const float g1 = g1p[0], g2 = g2p[0];
  { const int cl = t >> 3, k0 = (t & 7) << 5;
    const int c = c0 + cl;
    const float* wr = sew + (size_t)c*256 + k0;
    const float* pr = pooled + b*256 + k0;
    float part = 0.f;
    #pragma unroll
    for(int j = 0; j < 32; j += 4){
      float4 w4 = *(const float4*)(wr + j);
      float4 p4 = *(const float4*)(pr + j);
      part += w4.x*p4.x + w4.y*p4.y + w4.z*p4.z + w4.w*p4.w;
    }
    part += __shfl_xor(part, 1); part += __shfl_xor(part, 2); part += __shfl_xor(part, 4);
    if((t & 7) == 0){
      float a = part * (1.f/4096.f) + seb[c];
      gate_l[cl] = g2 / (1.f + __expf(-a));
    }
  }
  { const int ml = t >> 2, cg = (t & 3) << 3;
    const int gq = b*4096 + m0 + ml;
    const float l0 = lsav[gq], l1 = lsav[16384 + gq];
    const float inv = 1.f / (l0 + l1);
    const float w0 = l0*inv, w1 = l1*inv;
    const size_t base = ((size_t)gq << 8) + c0 + cg;
    union { uint4 u; u16 s[8]; } A0, A1;
    A0.u = *(const uint4*)(Op + base);
    A1.u = *(const uint4*)(Op + base + ((size_t)16384 << 8));
    #pragma unroll
    for(int i = 0; i < 8; ++i)
      tO[cg+i][ml] = w0*b2f(A0.s[i]) + w1*b2f(A1.s[i]);
    const u16* yrow = y_t + base;
    uint4 yu = *(const uint4*)yrow;
    tY[cg+0][ml]=b2f((u16)(yu.x & 0xffffu)); tY[cg+1][ml]=b2f((u16)(yu.x >> 16));
    tY[cg+2][ml]=b2f((u16)(yu.y & 0xffffu)); tY[cg+3][ml]=b2f((u16)(yu.y >> 16));
    tY[cg+4][ml]=b2f((u16)(yu.z & 0xffffu)); tY[cg+5][ml]=b2f((u16)(yu.z >> 16));
    tY[cg+6][ml]=b2f((u16)(yu.w & 0xffffu)); tY[cg+7][ml]=b2f((u16)(yu.w >> 16));
  }
  __syncthreads();
  { const int cl = t >> 3, mg = (t & 7) << 3;
    const int c = c0 + cl;
    const float gate = gate_l[cl];
    const float* xrow = x + ((size_t)(b*256 + c) << 12) + m0 + mg;
    float* orow = out + ((size_t)(b*256 + c) << 12) + m0 + mg;
    float4 x0 = *(const float4*)xrow, x1 = *(const float4*)(xrow + 4);
    float4 r0, r1;
    r0.x = g1*tO[cl][mg+0] + gate*tY[cl][mg+0] + x0.x;
    r0.y = g1*tO[cl][mg+1] + gate*tY[cl][mg+1] + x0.y;
    r0.z = g1*tO[cl][mg+2] + gate*tY[cl][mg+2] + x0.z;
    r0.w = g1*tO[cl][mg+3] + gate*tY[cl][mg+3] + x0.w;
    r1.x = g1*tO[cl][mg+4] + gate*tY[cl][mg+4] + x1.x;
    r1.y = g1*tO[cl][mg+5] + gate*tY[cl][mg+5] + x1.y;
    r1.z = g1*tO[cl][mg+6] + gate*tY[cl][mg+6] + x1.z;
    r1.w = g1*tO[cl][mg+7] + gate*tY[cl][mg+7] + x1.w;
    *(float4*)orow = r0;
    *(float4*)(orow + 4) = r1;
  }
}

extern "C" void kernel_launch(void* const* d_in, const int* in_sizes, int n_in,
                              void* d_out, int out_size, void* d_ws, size_t ws_size,
                              hipStream_t stream){
  (void)in_sizes; (void)n_in; (void)out_size; (void)ws_size;
  const float* x    = (const float*)d_in[0];
  const float* dw1w = (const float*)d_in[1];
  const float* dw1b = (const float*)d_in[2];
  const float* dw2w = (const float*)d_in[3];
  const float* dw2b = (const float*)d_in[4];
  const float* keyw = (const float*)d_in[5];
  const float* keyb = (const float*)d_in[6];
  const float* valw = (const float*)d_in[7];
  const float* valb = (const float*)d_in[8];
  const float* c1w  = (const float*)d_in[9];
  const float* c1b  = (const float*)d_in[10];
  const float* c2w  = (const float*)d_in[11];
  const float* c2b  = (const float*)d_in[12];
  const float* sew  = (const float*)d_in[13];
  const float* seb  = (const float*)d_in[14];
  const float* g1   = (const float*)d_in[15];
  const float* g2   = (const float*)d_in[16];
  float* out = (float*)d_out;

  char* w = (char*)d_ws;
  auto take = [&](size_t bytes) -> char* {
    char* p = w; w += (bytes + 255) & ~(size_t)255; return p;
  };
  u16*  Op   = (u16*)  take(33554432);  // 2 K-split partials (head); xp and qp alias inside (disjoint live ranges)
  u16*  q_t  = (u16*)  take(1048576);   // [4][4096][32] (scaled by log2e)
  u16*  k_t  = (u16*)  take(1048576);   // [4][4096][32]
  u16*  vt   = (u16*)  take(8388608);   // [4] fragment-order V
  u16*  t1   = (u16*)  take(524288);    // [4][4096][16]
  u16*  y_t  = (u16*)  take(8388608);   // [4][4096][256]; wB+wC alias its head (dead until conv2)
  u16*  kwt  = (u16*)  take(16384);
  u16*  vwt  = (u16*)  take(131072);
  u16*  w2t  = (u16*)  take(81920);
  float* pooled = (float*)take(4096);
  float* lsav   = (float*)take(262144); // [2][16384] used

  u16*  xp = Op;                          // dead after k_qconv_kv (halo zeroed in k_prep)
  u16*  qp = Op + 6062080;                // byte offset 12124160; dead after k_qfin
  u16*  wB = y_t;                         // [121][16][32][16]; y_t first written by conv2 (later)
  u16*  wC = y_t + 991232;                // [9][16][32][16]

  k_prep<<<9164, 256, 0, stream>>>(x, xp, dw1w, dw2w, c1w, keyw, valw, c2w, wB, wC, kwt, vwt, w2t, pooled);
  k_qconv_kv<<<1536, 256, 0, stream>>>(xp, wB, wC, qp, vwt, kwt, valb, keyb, vt, k_t);
  k_qfin<<<4096, 256, 0, stream>>>(qp, dw1b, dw2b, c1b, q_t, t1);
  k_attn_conv2<<<1280, 256, 0, stream>>>(q_t, k_t, vt, Op, lsav, t1, w2t, c2b, y_t, pooled);
  k_final<<<2048, 256, 0, stream>>>(Op, y_t, x, lsav, pooled, sew, seb, g1, g2, out);
}

// Round 14
// 234.898 us; speedup vs baseline: 1.0266x; 1.0266x over previous
//
#include <hip/hip_runtime.h>

typedef unsigned short u16;
typedef unsigned u32;
typedef __bf16 bf16x8 __attribute__((ext_vector_type(8)));
typedef float f32x4 __attribute__((ext_vector_type(4)));
typedef float f32x16 __attribute__((ext_vector_type(16)));

#define MFMA16(A,B,C) __builtin_amdgcn_mfma_f32_16x16x32_bf16((A),(B),(C),0,0,0)
#define MFMA32(A,B,C) __builtin_amdgcn_mfma_f32_32x32x16_bf16((A),(B),(C),0,0,0)

__device__ __forceinline__ u16 f2b(float f){
  union { float f; unsigned u; } X; X.f = f;
  unsigned r = X.u + 0x7FFFu + ((X.u >> 16) & 1u);
  return (u16)(r >> 16);
}
__device__ __forceinline__ float b2f(u16 h){
  union { unsigned u; float f; } X; X.u = ((unsigned)h) << 16; return X.f;
}
__device__ __forceinline__ bf16x8 ld_frag(const u16* p){
  union { uint4 u; bf16x8 v; } U; U.u = *(const uint4*)p; return U.v;
}
// pack two f32 -> one u32 of 2 bf16 (RNE). No builtin on gfx950 -> inline asm.
__device__ __forceinline__ u32 pkbf(float a, float b){
  u32 r; asm("v_cvt_pk_bf16_f32 %0, %1, %2" : "=v"(r) : "v"(a), "v"(b)); return r;
}
// swap lower-32-lane half of x with upper-32-lane half of y (both outputs usable)
__device__ __forceinline__ void pl32swap(u32& x, u32& y){
  auto r = __builtin_amdgcn_permlane32_swap(x, y, false, false);
  x = r[0]; y = r[1];
}
// async global->LDS, 16B per lane, wave-uniform LDS base + lane*16
__device__ __forceinline__ void gld16(const u16* g, u16* l){
  __builtin_amdgcn_global_load_lds(
      (const __attribute__((address_space(1))) u32*)g,
      (__attribute__((address_space(3))) u32*)l, 16, 0, 0);
}

// ---------------- prep bodies ----------------
// wB[tap121][chunk16][oc32][ci16]: oc<16 -> conv7 (zero-padded), oc>=16 -> conv11.
// wC[tap9][chunk16][oc32][ci16]:  oc<16 -> conv1, oc>=16 -> zero.
// w2t[co256][k160] TAP-MAJOR. (wB/wC alias y_t — kv runs concurrently with qconv.)
// tail ranges: pooled[1024] zero + xp HALO zero (replaces the 12MB memset; halo is
// disjoint from prep_x's interior writes, so no intra-kernel ordering needed).
__device__ __forceinline__ void prep_w_body(int i,
    const float* __restrict__ dw1, const float* __restrict__ dw2,
    const float* __restrict__ cw1, const float* __restrict__ kw,
    const float* __restrict__ vw,  const float* __restrict__ cw2,
    u16* __restrict__ wB, u16* __restrict__ wC,
    u16* __restrict__ kwt, u16* __restrict__ vwt, u16* __restrict__ w2t,
    float* __restrict__ pooled, u16* __restrict__ xp){
  const int NB = 991232, NC = 73728, NK = 8192, NV = 65536, N2 = 40960;
  if(i < NB){
    int tap = i >> 13, rem = i & 8191;
    int chunk = rem >> 9, r2 = rem & 511;
    int oc = r2 >> 4, ci = chunk*16 + (r2 & 15);
    int dy = tap / 11, dx = tap - dy*11;
    float v;
    if(oc < 16){
      v = (dy >= 2 && dy <= 8 && dx >= 2 && dx <= 8) ? dw1[(oc*256 + ci)*49 + (dy-2)*7 + (dx-2)] : 0.f;
    } else {
      v = dw2[((oc-16)*256 + ci)*121 + tap];
    }
    wB[i] = f2b(v);
    return;
  }
  i -= NB;
  if(i < NC){
    int tap = i >> 13, rem = i & 8191;
    int chunk = rem >> 9, r2 = rem & 511;
    int oc = r2 >> 4, ci = chunk*16 + (r2 & 15);
    wC[i] = (oc < 16) ? f2b(cw1[(oc*256 + ci)*9 + tap]) : (u16)0;
    return;
  }
  i -= NC;
  if(i < NK){ kwt[i] = f2b(kw[i]); return; }
  i -= NK;
  if(i < NV){ vwt[i] = f2b(vw[i]); return; }
  i -= NV;
  if(i < N2){
    int co = i/160, kk = i - co*160;
    int tap = kk >> 4, ci = kk & 15;
    w2t[i] = (tap < 9) ? f2b(cw2[co*144 + ci*9 + tap]) : (u16)0;
    return;
  }
  i -= N2;
  if(i < 1024){ pooled[i] = 0.f; return; }
  i -= 1024;
  if(i < 116736){   // xp halo: 4 b x 16 chunks x 1824 halo px, 32B each
    int b = i / 29184;
    int r1 = i - b*29184;
    int chunk = r1 / 1824;
    int p = r1 - chunk*1824;
    int y, x;
    if(p < 800){ int r = p / 80; x = p - r*80; y = (r < 5) ? r : r + 64; }
    else { int j = p - 800; int cc = j & 15; y = 5 + (j >> 4); x = (cc < 5) ? cc : cc + 64; }
    uint4* dst = (uint4*)&xp[(((size_t)(b*16 + chunk)*74 + y)*80 + x)*16];
    dst[0] = make_uint4(0u,0u,0u,0u);
    dst[1] = make_uint4(0u,0u,0u,0u);
    return;
  }
}

// x NCHW fp32 -> padded CHUNK-MAJOR xp[b][chunk16][y+5][x+5][ci16] bf16 (interior only)
__device__ __forceinline__ void prep_x_body(int bid, int t, float* tile /*[32][33] shared*/,
    const float* __restrict__ x, u16* __restrict__ xp){
  const int b = bid >> 10, rem = bid & 1023;
  const int c0 = (rem >> 7) << 5, m0 = (rem & 127) << 5;
  { const int cg = t >> 5, mm = t & 31;
    #pragma unroll
    for(int i=0;i<4;i++)
      tile[(cg*4+i)*33 + mm] = x[((size_t)(b*256 + c0 + cg*4 + i) << 12) + m0 + mm];
  }
  __syncthreads();
  { const int cp = (t & 15) << 1, mloc = t >> 4;
    #pragma unroll
    for(int half = 0; half < 2; ++half){
      const int ml = half*16 + mloc;
      const int m = m0 + ml;
      const int yy = (m >> 6) + 5, xx = (m & 63) + 5;
      const int ci = c0 + cp;
      const int chunk = ci >> 4, wi = ci & 15;
      u16 lo = f2b(tile[cp*33 + ml]), hi = f2b(tile[(cp+1)*33 + ml]);
      *(unsigned*)&xp[(((size_t)(b*16 + chunk)*74 + yy)*80 + xx)*16 + wi] = ((unsigned)hi << 16) | lo;
    }
  }
}

// ---------------- K_prep: fused prep_x + prep_w + pooled/halo zero ----------------
__global__ __launch_bounds__(256) void k_prep(
    const float* __restrict__ x, u16* __restrict__ xp,
    const float* __restrict__ dw1, const float* __restrict__ dw2,
    const float* __restrict__ cw1, const float* __restrict__ kw,
    const float* __restrict__ vw,  const float* __restrict__ cw2,
    u16* __restrict__ wB, u16* __restrict__ wC,
    u16* __restrict__ kwt, u16* __restrict__ vwt, u16* __restrict__ w2t,
    float* __restrict__ pooled){
  __shared__ float tile[32*33];
  const int bid = blockIdx.x;
  if(bid < 4096){
    prep_x_body(bid, threadIdx.x, tile, x, xp);
  } else {
    prep_w_body((bid - 4096)*256 + threadIdx.x, dw1, dw2, cw1, kw, vw, cw2, wB, wC, kwt, vwt, w2t, pooled, xp);
  }
}

// ---------------- qconv body: fused conv7+conv11+conv1, 32x32x16 MFMA ----------------
// The 242.5µs-verified structure (measured optimum of the tile-geometry space: r8's
// kq-split and r9's 2-row/wave both regressed via register squeeze). 4 output rows/block
// (512 qconv blocks = 2/CU); wave wv owns row y0+wv, BOTH x-halves (2 MFMAs per B-frag);
// fully unrolled dy with 2-deep register pipeline of the 11 B-frags.
__device__ __forceinline__ void qconv_body(int bid, int t, u16* buf /*35840B shared*/,
    const u16* __restrict__ xp, const u16* __restrict__ wB, const u16* __restrict__ wC,
    u16* __restrict__ qp){
  const int rg = bid & 15, b = (bid >> 4) & 3, kq = bid >> 6;
  const int y0 = rg << 2;
  const int wv = t >> 6, lane = t & 63;
  const int m = lane & 31, kh = lane >> 5;
  const int laneoff = m*16 + kh*8;
  const f32x16 z16 = {0.f,0.f,0.f,0.f,0.f,0.f,0.f,0.f,0.f,0.f,0.f,0.f,0.f,0.f,0.f,0.f};
  f32x16 accA = z16, accB = z16, acc1A = z16, acc1B = z16;

  #pragma unroll 1
  for(int c = 0; c < 2; ++c){
    const int chunk = kq*2 + c;
    const uint4* src = (const uint4*)(xp + ((size_t)((b*16 + chunk)*74 + y0))*1280);
    __syncthreads();
    for(int e = t; e < 2240; e += 256){
      ((uint4*)buf)[(e & 1)*1120 + (e >> 1)] = src[e];
    }
    __syncthreads();
    const u16* wBc = wB + chunk*512 + laneoff;
    const u16* wCc = wC + chunk*512 + laneoff;
    const u16* ap = buf + kh*8960 + (wv*80 + m)*8;
    bf16x8 Brow[2][11];
    #pragma unroll
    for(int dx = 0; dx < 11; ++dx) Brow[0][dx] = ld_frag(wBc + dx*8192);
    #pragma unroll
    for(int dy = 0; dy < 11; ++dy){
      if(dy < 10){
        const u16* wnext = wBc + (dy+1)*11*8192;
        #pragma unroll
        for(int dx = 0; dx < 11; ++dx) Brow[(dy+1)&1][dx] = ld_frag(wnext + dx*8192);
      }
      const u16* rowp = ap + dy*640;
      #pragma unroll
      for(int dx = 0; dx < 11; ++dx){
        bf16x8 B = Brow[dy&1][dx];
        bf16x8 A0 = ld_frag(rowp + dx*8);
        bf16x8 A1 = ld_frag(rowp + dx*8 + 256);
        accA = MFMA32(A0, B, accA);
        accB = MFMA32(A1, B, accB);
        if(dy >= 4 && dy <= 6 && dx >= 4 && dx <= 6){
          bf16x8 B1 = ld_frag(wCc + ((dy-4)*3 + (dx-4))*8192);
          acc1A = MFMA32(A0, B1, acc1A);
          acc1B = MFMA32(A1, B1, acc1B);
        }
      }
    }
  }

  u16* qb = qp + ((size_t)kq*16384 + (b << 12) + (y0 + wv)*64) * 48;
  #pragma unroll
  for(int reg = 0; reg < 16; ++reg){
    const int row = (reg & 3) + ((reg >> 2) << 3) + (kh << 2);
    qb[row*48 + m] = f2b(accA[reg]);
    qb[(32 + row)*48 + m] = f2b(accB[reg]);
    if(m < 16){
      qb[row*48 + 32 + m] = f2b(acc1A[reg]);
      qb[(32 + row)*48 + 32 + m] = f2b(acc1B[reg]);
    }
  }
}

// ---------------- kv body: 1x1 convs, 4-way ct-split ----------------
// vt written in MFMA-B-fragment order (k_attn stages it with a linear global_load_lds copy;
// zero LDS bank conflicts by construction).
__device__ __forceinline__ void kv_body(int bid, int tid,
    const u16* __restrict__ xp, const u16* __restrict__ vwt, const u16* __restrict__ kwt,
    const float* __restrict__ vb, const float* __restrict__ kb,
    u16* __restrict__ vt, u16* __restrict__ k_t){
  const int h = bid & 3, blk = (bid >> 2) & 63, b = bid >> 8;
  const int wv = tid >> 6, lane = tid & 63;
  const int col = lane & 15, quad = lane >> 4;
  const int m0 = (blk << 6) + (wv << 4);
  f32x4 z = {0.f,0.f,0.f,0.f};
  f32x4 av[4], ak[2];
  #pragma unroll
  for(int i=0;i<4;i++) av[i] = z;
  ak[0] = z; ak[1] = z;
  const int m = m0 + col;
  const int py = (m >> 6) + 5, pxx = (m & 63) + 5;
  #pragma unroll 1
  for(int ch = 0; ch < 8; ++ch){
    const int cio = ch*32 + quad*8;
    const int chunk = cio >> 4, wi = cio & 15;
    bf16x8 xf = ld_frag(xp + (((size_t)(b*16 + chunk)*74 + py)*80 + pxx)*16 + wi);
    #pragma unroll
    for(int ct2 = 0; ct2 < 4; ++ct2){
      bf16x8 wf = ld_frag(vwt + (((h*4 + ct2)*16 + col) << 8) + cio);
      av[ct2] = MFMA16(wf, xf, av[ct2]);
    }
    if(h == 0){
      #pragma unroll
      for(int kt = 0; kt < 2; ++kt){
        bf16x8 kf = ld_frag(kwt + ((kt*16 + col) << 8) + cio);
        ak[kt] = MFMA16(xf, kf, ak[kt]);
      }
    }
  }
  const size_t kgb = ((size_t)(b*256 + (m0 >> 4)));
  const int hi2 = col >> 3, j = col & 7;
  #pragma unroll
  for(int ct2 = 0; ct2 < 4; ++ct2){
    #pragma unroll
    for(int r = 0; r < 4; ++r){
      const int c = (h*4 + ct2)*16 + quad*4 + r;
      vt[((((kgb*8 + (c >> 5))*2 + hi2)*32) + (c & 31))*8 + j] = f2b(av[ct2][r] + vb[c]);
    }
  }
  if(h == 0){
    #pragma unroll
    for(int kt = 0; kt < 2; ++kt){
      #pragma unroll
      for(int r = 0; r < 4; ++r){
        const int mq = b*4096 + m0 + quad*4 + r;
        k_t[mq*32 + kt*16 + col] = f2b((ak[kt][r] + kb[kt*16 + col]) );
      }
    }
  }
}

// ---------------- K_qkv: fused qconv (bid<512) + kv (bid>=512) ----------------
// kv is independent of qconv (both read xp, write disjoint outputs) and qconv runs at
// only 2 blocks/CU — kv blocks fill the idle capacity instead of a serial launch.
__global__ __launch_bounds__(256, 2) void k_qconv_kv(
    const u16* __restrict__ xp, const u16* __restrict__ wB, const u16* __restrict__ wC,
    u16* __restrict__ qp,
    const u16* __restrict__ vwt, const u16* __restrict__ kwt,
    const float* __restrict__ vb, const float* __restrict__ kb,
    u16* __restrict__ vt, u16* __restrict__ k_t){
  __shared__ __align__(16) u16 buf[17920];   // used by qconv path only
  const int bid = blockIdx.x;
  if(bid < 512) qconv_body(bid, threadIdx.x, buf, xp, wB, wC, qp);
  else          kv_body(bid - 512, threadIdx.x, xp, vwt, kwt, vb, kb, vt, k_t);
}

// ---------------- K2b: combine 8 bf16 partials, bias, silu. Q scaled by log2(e) ----------------
__global__ __launch_bounds__(256) void k_qfin(
    const u16* __restrict__ qp, const float* __restrict__ b7,
    const float* __restrict__ b11, const float* __restrict__ b1,
    u16* __restrict__ q_t, u16* __restrict__ t1){
  const int t = threadIdx.x, wv = t >> 6, lane = t & 63;
  const int px = blockIdx.x*4 + wv;
  if(lane >= 48) return;
  const size_t off = (size_t)px*48 + lane;
  float s = 0.f;
  #pragma unroll
  for(int sp = 0; sp < 8; ++sp) s += b2f(qp[off + (size_t)sp*786432]);
  const float LOG2E = 1.44269504f;
  if(lane < 16){
    q_t[px*32 + lane] = f2b((s + b7[lane]) * LOG2E);
  } else if(lane < 32){
    q_t[px*32 + lane] = f2b((s + b11[lane - 16]) * LOG2E);
  } else {
    float v = s + b1[lane - 32];
    t1[px*16 + lane - 32] = f2b(v / (1.f + __expf(-v)));
  }
}

// ---------------- attn body: dedup softmax, counted-vmcnt pipeline (r5-verified) ----------------
// ks=2 (2048 keys / 32 iters per block). Exact r11-measured-best body: no setprio (r13
// measured it −3µs in this barrier-lockstep regime, m190-class), exp2f (r12's raw
// v_exp_f32 asm hid the TRANS result-read hazard -> corruption).
__device__ __forceinline__ void attn_body(int bid, int t, u16* Vs /*2x16384 u16 shared*/,
    const u16* __restrict__ q_t, const u16* __restrict__ k_t,
    const u16* __restrict__ vt, u16* __restrict__ Op,
    float* __restrict__ lsav){
  const int q0 = (bid & 31) << 7, b = (bid >> 5) & 3, ks = bid >> 7;  // ks 0..1
  const int wv = t >> 6, lane = t & 63;
  const int cq = lane & 31, hi = lane >> 5;

  const u16* qrow = q_t + ((size_t)(b*4096 + q0 + wv*32 + cq) << 5) + hi*8;
  const bf16x8 qf0 = ld_frag(qrow), qf1 = ld_frag(qrow + 16);
  const u16* kbase = k_t + ((size_t)(b*4096 + ks*2048 + cq) << 5) + hi*8;
  const u16* vsrc = vt + ((size_t)(b*256 + ks*128) << 12);

  const f32x16 z16 = {0.f,0.f,0.f,0.f,0.f,0.f,0.f,0.f,0.f,0.f,0.f,0.f,0.f,0.f,0.f,0.f};
  f32x16 acc[8];
  #pragma unroll
  for(int i=0;i<8;i++) acc[i] = z16;
  float lp0=0.f, lp1=0.f, lp2=0.f, lp3=0.f;

  // prologue: stage iter 0 (32KB linear), then K frags for iter 0 (order pinned)
  #pragma unroll
  for(int s = 0; s < 8; ++s)
    gld16(vsrc + (size_t)(s*256 + t)*8, Vs + (s*256 + (wv << 6))*8);
  __builtin_amdgcn_sched_barrier(0);
  bf16x8 kc0 = ld_frag(kbase),        kc1 = ld_frag(kbase + 16);
  bf16x8 kc2 = ld_frag(kbase + 1024), kc3 = ld_frag(kbase + 1040);

  #pragma unroll 1
  for(int it = 0; it < 32; ++it){
    const int cur = it & 1;
    asm volatile("s_waitcnt vmcnt(4)" ::: "memory");   // stage(it) landed; K(it) may remain
    __builtin_amdgcn_s_barrier();
    __builtin_amdgcn_sched_barrier(0);
    const bf16x8 ka0 = kc0, ka1 = kc1, ka2 = kc2, ka3 = kc3;
    if(it < 31){
      const u16* gb = vsrc + ((size_t)(it + 1) << 14);
      #pragma unroll
      for(int s = 0; s < 8; ++s)
        gld16(gb + (size_t)(s*256 + t)*8, Vs + (cur ^ 1)*16384 + (s*256 + (wv << 6))*8);
      __builtin_amdgcn_sched_barrier(0);   // pin gld16 before kc loads (in-order vmcnt retire)
      const u16* kpn = kbase + ((size_t)(it + 1) << 11);
      kc0 = ld_frag(kpn);        kc1 = ld_frag(kpn + 16);
      kc2 = ld_frag(kpn + 1024); kc3 = ld_frag(kpn + 1040);
    }
    const u16* Vb = Vs + cur*16384 + hi*256 + cq*8;   // lane-linear frag base
    #pragma unroll
    for(int sub = 0; sub < 2; ++sub){
      const bf16x8 kf0 = sub ? ka2 : ka0;
      const bf16x8 kf1 = sub ? ka3 : ka1;
      f32x16 S = MFMA32(kf0, qf0, z16);
      S = MFMA32(kf1, qf1, S);
      float p[16];
      #pragma unroll
      for(int rr = 0; rr < 16; ++rr) p[rr] = exp2f(S[rr]);
      #pragma unroll
      for(int rr = 0; rr < 16; rr += 4){
        lp0 += p[rr]; lp1 += p[rr+1]; lp2 += p[rr+2]; lp3 += p[rr+3];
      }
      u32 a0 = pkbf(p[0], p[1]),   b0 = pkbf(p[4], p[5]);
      u32 a1 = pkbf(p[2], p[3]),   b1 = pkbf(p[6], p[7]);
      u32 c0 = pkbf(p[8], p[9]),   d0 = pkbf(p[12], p[13]);
      u32 c1 = pkbf(p[10], p[11]), d1 = pkbf(p[14], p[15]);
      pl32swap(a0, b0); pl32swap(a1, b1); pl32swap(c0, d0); pl32swap(c1, d1);
      union { u32 w[4]; bf16x8 v; } A0, A1;
      A0.w[0] = a0; A0.w[1] = a1; A0.w[2] = b0; A0.w[3] = b1;
      A1.w[0] = c0; A1.w[1] = c1; A1.w[2] = d0; A1.w[3] = d1;
      const u16* f0 = Vb + sub*8192;
      #pragma unroll
      for(int ct = 0; ct < 8; ++ct){
        acc[ct] = MFMA32(A0.v, ld_frag(f0 + ct*512),        acc[ct]);
        acc[ct] = MFMA32(A1.v, ld_frag(f0 + 4096 + ct*512), acc[ct]);
      }
    }
  }

  float lt = lp0 + lp1 + lp2 + lp3;
  lt += __shfl_xor(lt, 32);
  if(lane < 32)
    lsav[ks*16384 + b*4096 + q0 + wv*32 + cq] = lt;
  const float invl = 1.f / lt;
  u16* ob = Op + (((size_t)(ks*16384 + b*4096 + q0 + wv*32)) << 8) + cq;
  #pragma unroll
  for(int reg = 0; reg < 16; ++reg){
    const int row = (reg & 3) + ((reg >> 2) << 3) + (hi << 2);
    const float inv = __shfl(invl, row);
    u16* orow = ob + ((size_t)row << 8);
    #pragma unroll
    for(int ct = 0; ct < 8; ++ct)
      orow[ct*32] = f2b(acc[ct][reg] * inv);
  }
}

// ---------------- conv2 body: 3x3 16->256, tap-major im2col, 4-way oc-split ----------------
__device__ __forceinline__ void conv2_body(int bid, int t, u16* im_s /*[64][168]*/, float* pool_s /*[64]*/,
    const u16* __restrict__ t1, const u16* __restrict__ w2t, const float* __restrict__ b2,
    u16* __restrict__ y_t, float* __restrict__ pooled){
  const int h = bid & 3, y = (bid >> 2) & 63, b = bid >> 8;
  if(t < 64) pool_s[t] = 0.f;
  const u16* t1b = t1 + ((size_t)(b*4096) << 4);
  { const int px = t >> 2, ci0 = (t & 3) << 2;
    #pragma unroll
    for(int tap = 0; tap < 9; ++tap){
      const int ky = (tap*11) >> 5, kx = tap - ky*3;
      const int ryy = y + ky - 1, rxx = px + kx - 1;
      uint2 val = make_uint2(0u, 0u);
      if((unsigned)ryy < 64u && (unsigned)rxx < 64u)
        val = *(const uint2*)(t1b + (((ryy << 6) + rxx) << 4) + ci0);
      *(uint2*)(im_s + px*168 + tap*16 + ci0) = val;
    }
    for(int e = t; e < 1024; e += 256){ im_s[(e >> 4)*168 + 144 + (e & 15)] = 0; }
  }
  __syncthreads();
  const int wv = t >> 6, lane = t & 63, col = lane & 15, quad = lane >> 4;
  const f32x4 z = {0.f,0.f,0.f,0.f};
  f32x4 acc[4];
  #pragma unroll
  for(int i=0;i<4;i++) acc[i] = z;
  #pragma unroll
  for(int ch = 0; ch < 5; ++ch){
    bf16x8 af = ld_frag(im_s + (wv*16 + col)*168 + ch*32 + quad*8);
    #pragma unroll
    for(int j = 0; j < 4; ++j){
      bf16x8 wf = ld_frag(w2t + ((h*4 + j)*16 + col)*160 + ch*32 + quad*8);
      acc[j] = MFMA16(af, wf, acc[j]);
    }
  }
  const int m0 = (y << 6) + (wv << 4) + (quad << 2);
  #pragma unroll
  for(int j = 0; j < 4; ++j){
    const int c = (h*4 + j)*16 + col;
    const float bias = b2[c];
    float s = 0.f;
    #pragma unroll
    for(int r = 0; r < 4; ++r){
      float v = acc[j][r] + bias;
      y_t[((size_t)(b*4096 + m0 + r) << 8) + c] = f2b(v);
      s += v;
    }
    s += __shfl_xor(s, 16); s += __shfl_xor(s, 32);
    if(quad == 0) atomicAdd(&pool_s[c - h*64], s);
  }
  __syncthreads();
  if(t < 64) atomicAdd(&pooled[b*256 + h*64 + t], pool_s[t]);
}

// ---------------- K_ac: fused attn (bid<256) + conv2 (bid>=256) ----------------
// attn grid 256 (ks=2); conv2's 1024 blocks fill the freed residency. Shared mem union:
// attn uses all 64KB; conv2 carves im (21504B) + pool (256B) from the same block.
__global__ __launch_bounds__(256, 2) void k_attn_conv2(
    const u16* __restrict__ q_t, const u16* __restrict__ k_t,
    const u16* __restrict__ vt, u16* __restrict__ Op, float* __restrict__ lsav,
    const u16* __restrict__ t1, const u16* __restrict__ w2t, const float* __restrict__ b2,
    u16* __restrict__ y_t, float* __restrict__ pooled){
  __shared__ __align__(16) u16 shm[32768];   // 65536 B
  const int bid = blockIdx.x;
  if(bid < 256) attn_body(bid, threadIdx.x, shm, q_t, k_t, vt, Op, lsav);
  else          conv2_body(bid - 256, threadIdx.x, shm, (float*)(shm + 10752), t1, w2t, b2, y_t, pooled);
}

// ---------------- K7: final combine + fused 2-way K-split merge + fused SE gate ----------------
__global__ __launch_bounds__(256) void k_final(
    const u16* __restrict__ Op, const u16* __restrict__ y_t, const float* __restrict__ x,
    const float* __restrict__ lsav, const float* __restrict__ pooled,
    const float* __restrict__ sew, const float* __restrict__ seb,
    const float* __restrict__ g1p, const float* __restrict__ g2p,
    float* __restrict__ out){
  __shared__ float tO[32][65];
  __shared__ float tY[32][65];
  __shared__ float gate_l[32];
  const int bid = blockIdx.x;
  const int b = bid >> 9, rem = bid & 511;
  const int c0 = (rem >> 6) << 5, m0 = (rem & 63) << 6;
  const int t = threadIdx.x;
  const float g1 = g1p[0], g2 = g2p[0];
  { const int cl = t >> 3, k0 = (t & 7) << 5;
    const int c = c0 + cl;
    const float* wr = sew + (size_t)c*256 + k0;
    const float* pr = pooled + b*256 + k0;
    float part = 0.f;
    #pragma unroll
    for(int j = 0; j < 32; j += 4){
      float4 w4 = *(const float4*)(wr + j);
      float4 p4 = *(const float4*)(pr + j);
      part += w4.x*p4.x + w4.y*p4.y + w4.z*p4.z + w4.w*p4.w;
    }
    part += __shfl_xor(part, 1); part += __shfl_xor(part, 2); part += __shfl_xor(part, 4);
    if((t & 7) == 0){
      float a = part * (1.f/4096.f) + seb[c];
      gate_l[cl] = g2 / (1.f + __expf(-a));
    }
  }
  { const int ml = t >> 2, cg = (t & 3) << 3;
    const int gq = b*4096 + m0 + ml;
    const float l0 = lsav[gq], l1 = lsav[16384 + gq];
    const float inv = 1.f / (l0 + l1);
    const float w0 = l0*inv, w1 = l1*inv;
    const size_t base = ((size_t)gq << 8) + c0 + cg;
    union { uint4 u; u16 s[8]; } A0, A1;
    A0.u = *(const uint4*)(Op + base);
    A1.u = *(const uint4*)(Op + base + ((size_t)16384 << 8));
    #pragma unroll
    for(int i = 0; i < 8; ++i)
      tO[cg+i][ml] = w0*b2f(A0.s[i]) + w1*b2f(A1.s[i]);
    const u16* yrow = y_t + base;
    uint4 yu = *(const uint4*)yrow;
    tY[cg+0][ml]=b2f((u16)(yu.x & 0xffffu)); tY[cg+1][ml]=b2f((u16)(yu.x >> 16));
    tY[cg+2][ml]=b2f((u16)(yu.y & 0xffffu)); tY[cg+3][ml]=b2f((u16)(yu.y >> 16));
    tY[cg+4][ml]=b2f((u16)(yu.z & 0xffffu)); tY[cg+5][ml]=b2f((u16)(yu.z >> 16));
    tY[cg+6][ml]=b2f((u16)(yu.w & 0xffffu)); tY[cg+7][ml]=b2f((u16)(yu.w >> 16));
  }
  __syncthreads();
  { const int cl = t >> 3, mg = (t & 7) << 3;
    const int c = c0 + cl;
    const float gate = gate_l[cl];
    const float* xrow = x + ((size_t)(b*256 + c) << 12) + m0 + mg;
    float* orow = out + ((size_t)(b*256 + c) << 12) + m0 + mg;
    float4 x0 = *(const float4*)xrow, x1 = *(const float4*)(xrow + 4);
    float4 r0, r1;
    r0.x = g1*tO[cl][mg+0] + gate*tY[cl][mg+0] + x0.x;
    r0.y = g1*tO[cl][mg+1] + gate*tY[cl][mg+1] + x0.y;
    r0.z = g1*tO[cl][mg+2] + gate*tY[cl][mg+2] + x0.z;
    r0.w = g1*tO[cl][mg+3] + gate*tY[cl][mg+3] + x0.w;
    r1.x = g1*tO[cl][mg+4] + gate*tY[cl][mg+4] + x1.x;
    r1.y = g1*tO[cl][mg+5] + gate*tY[cl][mg+5] + x1.y;
    r1.z = g1*tO[cl][mg+6] + gate*tY[cl][mg+6] + x1.z;
    r1.w = g1*tO[cl][mg+7] + gate*tY[cl][mg+7] + x1.w;
    *(float4*)orow = r0;
    *(float4*)(orow + 4) = r1;
  }
}

extern "C" void kernel_launch(void* const* d_in, const int* in_sizes, int n_in,
                              void* d_out, int out_size, void* d_ws, size_t ws_size,
                              hipStream_t stream){
  (void)in_sizes; (void)n_in; (void)out_size; (void)ws_size;
  const float* x    = (const float*)d_in[0];
  const float* dw1w = (const float*)d_in[1];
  const float* dw1b = (const float*)d_in[2];
  const float* dw2w = (const float*)d_in[3];
  const float* dw2b = (const float*)d_in[4];
  const float* keyw = (const float*)d_in[5];
  const float* keyb = (const float*)d_in[6];
  const float* valw = (const float*)d_in[7];
  const float* valb = (const float*)d_in[8];
  const float* c1w  = (const float*)d_in[9];
  const float* c1b  = (const float*)d_in[10];
  const float* c2w  = (const float*)d_in[11];
  const float* c2b  = (const float*)d_in[12];
  const float* sew  = (const float*)d_in[13];
  const float* seb  = (const float*)d_in[14];
  const float* g1   = (const float*)d_in[15];
  const float* g2   = (const float*)d_in[16];
  float* out = (float*)d_out;

  char* w = (char*)d_ws;
  auto take = [&](size_t bytes) -> char* {
    char* p = w; w += (bytes + 255) & ~(size_t)255; return p;
  };
  u16*  Op   = (u16*)  take(33554432);  // 2 K-split partials (head); xp and qp alias inside (disjoint live ranges)
  u16*  q_t  = (u16*)  take(1048576);   // [4][4096][32] (scaled by log2e)
  u16*  k_t  = (u16*)  take(1048576);   // [4][4096][32]
  u16*  vt   = (u16*)  take(8388608);   // [4] fragment-order V
  u16*  t1   = (u16*)  take(524288);    // [4][4096][16]
  u16*  y_t  = (u16*)  take(8388608);   // [4][4096][256]; wB+wC alias its head (dead until conv2)
  u16*  kwt  = (u16*)  take(16384);
  u16*  vwt  = (u16*)  take(131072);
  u16*  w2t  = (u16*)  take(81920);
  float* pooled = (float*)take(4096);
  float* lsav   = (float*)take(262144); // [2][16384] used

  u16*  xp = Op;                          // dead after k_qconv_kv (halo zeroed in k_prep)
  u16*  qp = Op + 6062080;                // byte offset 12124160; dead after k_qfin
  u16*  wB = y_t;                         // [121][16][32][16]; y_t first written by conv2 (later)
  u16*  wC = y_t + 991232;                // [9][16][32][16]

  k_prep<<<9164, 256, 0, stream>>>(x, xp, dw1w, dw2w, c1w, keyw, valw, c2w, wB, wC, kwt, vwt, w2t, pooled);
  k_qconv_kv<<<1536, 256, 0, stream>>>(xp, wB, wC, qp, vwt, kwt, valb, keyb, vt, k_t);
  k_qfin<<<4096, 256, 0, stream>>>(qp, dw1b, dw2b, c1b, q_t, t1);
  k_attn_conv2<<<1280, 256, 0, stream>>>(q_t, k_t, vt, Op, lsav, t1, w2t, c2b, y_t, pooled);
  k_final<<<2048, 256, 0, stream>>>(Op, y_t, x, lsav, pooled, sew, seb, g1, g2, out);
}